// Round 6
// baseline (173.165 us; speedup 1.0000x reference)
//
#include <hip/hip_runtime.h>

#define B_ 32
#define C_ 80
#define T_ 2048
#define W_ 128
#define H_ 512
#define K_ 5

#define KTOT 400          // C_*K_
#define NKI  13           // K iterations of 32
#define TM   128
#define TN   128
#define ITER_STRIDE (2 * 4 * 64 * 8)               // Bf elems per K-iter per nt
#define BF_ELEMS  (4 * NKI * ITER_STRIDE)          // [nt][it][w2][j][lane][8] = 212992

// prep_all block-role boundaries
#define RB_FEAT   1024                             // feat transpose blocks
#define RB_BFRAG  (RB_FEAT + BF_ELEMS / 256)       // +832 = 1856
#define RB_WORDS  (RB_BFRAG + B_)                  // +32  = 1888

#define TILE_S 88                                  // 80 + 8 pad: reduces LDS write conflict, keeps 16B f4v alignment

typedef _Float16 half8 __attribute__((ext_vector_type(8)));
typedef float    f4v   __attribute__((ext_vector_type(4)));

// ---------------------------------------------------------------------------
// prep_all: one dispatch, three roles by blockIdx.x (unchanged)
// ---------------------------------------------------------------------------
__global__ __launch_bounds__(256) void prep_all(
    const float* __restrict__ feat, const float* __restrict__ enc_w,
    const int* __restrict__ bounds, const int* __restrict__ lengths,
    _Float16* __restrict__ featT, _Float16* __restrict__ Bf,
    int* __restrict__ word_of, float* __restrict__ inv_cnt)
{
    __shared__ _Float16 tile[64 * TILE_S];
    const int bid = blockIdx.x;
    const int tid = threadIdx.x;

    if (bid < RB_FEAT) {
        const int b = bid >> 5, tc = bid & 31;
        const int t0 = tc * 64;
        for (int idx = tid; idx < 80 * 64; idx += 256) {
            int cc = idx >> 6, tt = idx & 63;                  // coalesced over tt
            float v = feat[((size_t)b * C_ + cc) * T_ + t0 + tt];
            tile[tt * TILE_S + cc] = (_Float16)v;
        }
        __syncthreads();
        for (int idx = tid; idx < 64 * 10; idx += 256) {
            int tt = idx / 10, g = idx % 10;                   // coalesced writes
            *(f4v*)(featT + ((size_t)b * T_ + t0 + tt) * C_ + g * 8) =
                *(const f4v*)(tile + tt * TILE_S + g * 8);
        }
    } else if (bid < RB_BFRAG) {
        int idx = (bid - RB_FEAT) * 256 + tid;                 // < BF_ELEMS exactly
        int e  = idx & 7;
        int l  = (idx >> 3) & 63;
        int j  = (idx >> 9) & 3;
        int w2 = (idx >> 11) & 1;
        int it = (idx >> 12) % NKI;
        int nt = idx / (NKI << 12);
        int h  = nt * 128 + w2 * 64 + j * 16 + (l & 15);
        int kc = it * 32 + (l >> 4) * 8 + e;
        float v = 0.f;
        if (kc < KTOT) v = enc_w[(h * C_ + kc % 80) * K_ + kc / 80];
        Bf[idx] = (_Float16)v;
    } else {
        const int b = bid - RB_BFRAG;
        int* wob = word_of + b * T_;
        for (int t = tid; t < T_; t += 256) wob[t] = -1;
        __syncthreads();
        if (tid < W_) {
            const int len = lengths[b];
            int s = bounds[(b * 2 + 0) * W_ + tid];
            int e = bounds[(b * 2 + 1) * W_ + tid];
            s = max(s, 0); e = min(e, T_);
            bool valid = (tid < len) && (e > s);
            inv_cnt[b * W_ + tid] = valid ? 1.f / (float)(e - s) : 0.f;
            if (valid)
                for (int t = s; t < e; ++t) wob[t] = tid;      // disjoint words
        }
    }
}

// ---------------------------------------------------------------------------
// Implicit-GEMM conv (f16 MFMA) + bias + ReLU + word mean-pool into wemb.
// R6: NO LDS, NO barrier. A fragments are loaded per-lane directly from
// featT (L2-resident; XCD-colocated): addr = (rt-2)*80 + it*32 + q*8,
// where rt = t0 + wm + ml + i*16. An 8-f16 run never crosses a K_-tap
// boundary (80 % 8 == 0), so SAME-pad handling is a per-lane select
// (tsrc in [0,T)) needed only in edge blocks -- wave-uniform branch.
// Pad-K columns (kc >= 400) multiply B==0, so A only needs addr clamping.
// Each block is a pure 13-iter load/MFMA stream: fully overlappable
// across 12 waves/CU, no serial stage-drain phase. 3 blocks/CU (LDS=0).
// ---------------------------------------------------------------------------
__global__ __launch_bounds__(256, 3) void gemm_enc(
    const _Float16* __restrict__ featT,   // (B,T,C)
    const _Float16* __restrict__ Bf,      // wave-order fragments (padded +2 iters)
    const float*    __restrict__ enc_b,   // (H)
    const int*      __restrict__ word_of, // (B,T)
    const float*    __restrict__ inv_cnt, // (B,W)
    float*          __restrict__ wemb)    // (B,W,H)
{
    const int tid = threadIdx.x;
    // bijective XCD co-location remap: all 4 nt of one g=(b,mt) share bid%8
    const int bid = blockIdx.x;                   // 0..2047
    const int xcd = bid & 7;
    const int u   = bid >> 3;                     // 0..255
    const int nt  = u & 3;
    const int g   = xcd + ((u >> 2) << 3);        // 0..511
    const int b   = g >> 4;
    const int mt  = g & 15;
    const int t0 = mt * TM;
    const int h0 = nt * TN;

    const int lane = tid & 63;
    const int wid  = tid >> 6;
    const int wm = (wid >> 1) * 64;
    const int wn = (wid & 1) * 64;
    const int w2 = wid & 1;
    const int ml = lane & 15;
    const int q  = lane >> 4;

    // ---- B fragment stream: issue it0/it1 preloads first ----
    const half8* bfp = (const half8*)(Bf + (((nt * NKI) * 2 + w2) * 4 * 64 + lane) * 8);
    half8 bcur[4], bnxt[4];
    #pragma unroll
    for (int j = 0; j < 4; ++j) bcur[j] = bfp[j * 64];
    #pragma unroll
    for (int j = 0; j < 4; ++j) bnxt[j] = bfp[512 + j * 64];

    // ---- A direct-load setup ----
    const _Float16* fb0 = featT + (size_t)b * T_ * C_;
    const int rtb   = t0 + wm + ml;                  // output row for i=0
    const int gbase = (rtb - 2) * C_ + q * 8;        // f16 units, may be <0 at mt==0
    const bool edge_lo = (mt == 0  && wm == 0);      // i==0 rows may read t<0
    const bool edge_hi = (mt == 15 && wm == 64);     // i==3 rows may read t>=T
    const int gmax = T_ * C_ - 8;

    // ---- epilogue scalar prefetch (overlaps A/B stream) ----
    const int bT = b * T_;
    const int bW = b * W_;
    int wlo[4], whi[4];
    unsigned ownm = 0;
    {
        int wpv[4], wnx[4];
        #pragma unroll
        for (int i = 0; i < 4; ++i) {
            const int tg = t0 + wm + i * 16;
            wlo[i] = word_of[bT + tg];
            whi[i] = word_of[bT + tg + 15];
            wpv[i] = (tg == 0)       ? -2 : word_of[bT + tg - 1];
            wnx[i] = (tg + 16 >= T_) ? -2 : word_of[bT + tg + 16];
        }
        #pragma unroll
        for (int i = 0; i < 4; ++i)
            if (wpv[i] != wlo[i] && wnx[i] != wlo[i]) ownm |= (1u << i);
    }

    f4v acc[4][4] = {};

    // A loader: compile-time (i, masked); runtime it
#define LOAD_A(dst, itv)                                                      \
    {                                                                         \
        _Pragma("unroll")                                                     \
        for (int i = 0; i < 4; ++i) {                                         \
            int ga = gbase + i * (16 * C_) + (itv) * 32;                      \
            if ((i == 0 && edge_lo) || (i == 3 && edge_hi)) {                 \
                int gac = min(max(ga, 0), gmax);                              \
                half8 v = *(const half8*)(fb0 + gac);                         \
                int dt = ((itv) * 32 + q * 8) / 80 - 2;                       \
                int tsrc = rtb + i * 16 + dt;                                 \
                if ((unsigned)tsrc >= (unsigned)T_) v = (half8){};            \
                dst[i] = v;                                                   \
            } else {                                                          \
                dst[i] = *(const half8*)(fb0 + ga);                           \
            }                                                                 \
        }                                                                     \
    }

    // preload A(it0)
    half8 acur[4];
    LOAD_A(acur, 0)

    #pragma unroll
    for (int it = 0; it < NKI; ++it) {
        half8 anxt[4], bnn[4];
        if (it < NKI - 1) {
            LOAD_A(anxt, it + 1)
        }
        {                                // B(it+2); Bf padded +2 iters
            const half8* bn = bfp + (it + 2) * 512;
            #pragma unroll
            for (int j = 0; j < 4; ++j) bnn[j] = bn[j * 64];
        }
        #pragma unroll
        for (int i = 0; i < 4; ++i)
            #pragma unroll
            for (int j = 0; j < 4; ++j)
                acc[i][j] = __builtin_amdgcn_mfma_f32_16x16x32_f16(acur[i], bcur[j], acc[i][j], 0, 0, 0);
        if (it < NKI - 1) {
            #pragma unroll
            for (int i = 0; i < 4; ++i) acur[i] = anxt[i];
        }
        #pragma unroll
        for (int j = 0; j < 4; ++j) { bcur[j] = bnxt[j]; bnxt[j] = bnn[j]; }
    }
#undef LOAD_A

    // ---- epilogue: bias + ReLU + mean-pool (batched loads, then pure VALU) ----
    float bias[4], invp[4];
    #pragma unroll
    for (int j = 0; j < 4; ++j) bias[j] = enc_b[h0 + wn + j * 16 + ml];
    #pragma unroll
    for (int i = 0; i < 4; ++i) invp[i] = inv_cnt[bW + max(wlo[i], 0)];

    #pragma unroll
    for (int i = 0; i < 4; ++i) {
        const int tg = t0 + wm + i * 16;
        const int w0  = wlo[i];
        const int w15 = whi[i];
        if (w0 == w15) {
            if (w0 >= 0) {
                const float inv = invp[i];
                const bool own = (ownm >> i) & 1;
                #pragma unroll
                for (int j = 0; j < 4; ++j) {
                    float s = 0.f;
                    #pragma unroll
                    for (int r = 0; r < 4; ++r) s += fmaxf(acc[i][j][r] + bias[j], 0.f);
                    s += __shfl_down(s, 32, 64);
                    s += __shfl_down(s, 16, 64);
                    if (q == 0) {
                        float val = s * inv;
                        float* dst = &wemb[(size_t)(bW + w0) * H_ + h0 + wn + j * 16 + ml];
                        if (own) *dst = val;                    // sole owner
                        else atomicAdd(dst, val);
                    }
                }
            }
        } else {
            #pragma unroll
            for (int j = 0; j < 4; ++j) {
                #pragma unroll
                for (int r = 0; r < 4; ++r) {
                    int t = tg + q * 4 + r;
                    int w = word_of[bT + t];
                    if (w >= 0)
                        atomicAdd(&wemb[(size_t)(bW + w) * H_ + h0 + wn + j * 16 + ml],
                                  fmaxf(acc[i][j][r] + bias[j], 0.f) * inv_cnt[bW + w]);
                }
            }
        }
    }
}

// ---------------------------------------------------------------------------
// Decoder: 512 blocks (b x 16 chunks of 8 words) for latency-hiding
// ---------------------------------------------------------------------------
__global__ __launch_bounds__(256) void dec_all(const float* __restrict__ wemb,
                                               const float* __restrict__ dec_w,
                                               const float* __restrict__ dec_b,
                                               float* __restrict__ out) {
    __shared__ float sdw[H_ * K_];       // 10.2 KB
    __shared__ float se[16][8];          // 12 rows used, k-stride 8
    const int bid = blockIdx.x;          // b*16 + ch
    const int b = bid >> 4, ch = bid & 15;
    const int w0 = ch * 8;
    for (int idx = threadIdx.x; idx < H_ * K_; idx += 256) sdw[idx] = dec_w[idx];
    __syncthreads();
    const int wid = threadIdx.x >> 6, lane = threadIdx.x & 63;
    for (int row = wid; row < 12; row += 4) {
        int wq = w0 - 2 + row;
        float a[K_] = {};
        if (wq >= 0 && wq < W_) {
            const float* src = wemb + ((size_t)b * W_ + wq) * H_;
            #pragma unroll
            for (int r = 0; r < H_ / 64; ++r) {
                int h = r * 64 + lane;
                float v = src[h];
                #pragma unroll
                for (int k = 0; k < K_; ++k) a[k] += v * sdw[h * K_ + k];
            }
        }
        #pragma unroll
        for (int k = 0; k < K_; ++k) {
            #pragma unroll
            for (int off = 32; off > 0; off >>= 1) a[k] += __shfl_down(a[k], off, 64);
        }
        if (lane == 0) {
            #pragma unroll
            for (int k = 0; k < K_; ++k) se[row][k] = a[k];
        }
    }
    __syncthreads();
    if (threadIdx.x < 8) {
        int wl = threadIdx.x;
        float acc = dec_b[0];
        #pragma unroll
        for (int k = 0; k < K_; ++k) acc += se[wl + k][k];
        out[b * W_ + w0 + wl] = acc;
    }
}

// ---------------------------------------------------------------------------
extern "C" void kernel_launch(void* const* d_in, const int* in_sizes, int n_in,
                              void* d_out, int out_size, void* d_ws, size_t ws_size,
                              hipStream_t stream) {
    const float* feat    = (const float*)d_in[0];
    const int*   bounds  = (const int*)  d_in[1];
    const int*   lengths = (const int*)  d_in[2];
    const float* enc_w   = (const float*)d_in[3];
    const float* enc_b   = (const float*)d_in[4];
    const float* dec_w   = (const float*)d_in[5];
    const float* dec_b   = (const float*)d_in[6];
    float* out = (float*)d_out;

    char* p = (char*)d_ws;
    _Float16* featT = (_Float16*)p;  p += (size_t)B_ * T_ * C_ * 2;                 // 10.49 MB
    _Float16* Bf    = (_Float16*)p;  p += (size_t)(BF_ELEMS + 2 * ITER_STRIDE) * 2; // 0.44 MB (+2-iter pad)
    int* word_of    = (int*)p;       p += (size_t)B_ * T_ * 4;                      // 0.26 MB
    float* inv_cnt  = (float*)p;     p += (size_t)B_ * W_ * 4;                      // 16 KB
    float* wemb     = (float*)p;                                                    // 8.39 MB (no pre-zero needed)

    prep_all<<<RB_WORDS, 256, 0, stream>>>(feat, enc_w, bounds, lengths,
                                           featT, Bf, word_of, inv_cnt);
    gemm_enc<<<B_ * (T_ / TM) * (H_ / TN), 256, 0, stream>>>(
        featT, Bf, enc_b, word_of, inv_cnt, wemb);
    dec_all<<<B_ * 16, 256, 0, stream>>>(wemb, dec_w, dec_b, out);
}

// Round 7
// 115.470 us; speedup vs baseline: 1.4996x; 1.4996x over previous
//
#include <hip/hip_runtime.h>

#define B_ 32
#define C_ 80
#define T_ 2048
#define W_ 128
#define H_ 512
#define K_ 5

#define KTOT 400          // C_*K_
#define NKI  13           // K iterations of 32
#define TM   128
#define TN   128
#define SF_STRIDE 80      // == C_: makes staging + A addressing exactly linear
#define SF_ROWS   136     // 128 + 4 halo + slack; 136*80 f16 = 21760 B
#define SF_ELEMS  (SF_ROWS * SF_STRIDE)
#define ITER_STRIDE (2 * 4 * 64 * 8)               // Bf elems per K-iter per nt
#define BF_ELEMS  (4 * NKI * ITER_STRIDE)          // [nt][it][w2][j][lane][8] = 212992

// prep_all block-role boundaries
#define RB_FEAT   1024                             // feat transpose blocks
#define RB_BFRAG  (RB_FEAT + BF_ELEMS / 256)       // +832 = 1856
#define RB_WORDS  (RB_BFRAG + B_)                  // +32  = 1888

#define TILE_S 88                                  // 80 + 8 pad: reduces LDS write conflict, keeps 16B f4v alignment

typedef _Float16 half8 __attribute__((ext_vector_type(8)));
typedef float    f4v   __attribute__((ext_vector_type(4)));

typedef const __attribute__((address_space(1))) unsigned int guint;
typedef __attribute__((address_space(3))) unsigned int luint;

// ---------------------------------------------------------------------------
// prep_all: one dispatch, three roles by blockIdx.x (unchanged)
// ---------------------------------------------------------------------------
__global__ __launch_bounds__(256) void prep_all(
    const float* __restrict__ feat, const float* __restrict__ enc_w,
    const int* __restrict__ bounds, const int* __restrict__ lengths,
    _Float16* __restrict__ featT, _Float16* __restrict__ Bf,
    int* __restrict__ word_of, float* __restrict__ inv_cnt)
{
    __shared__ _Float16 tile[64 * TILE_S];
    const int bid = blockIdx.x;
    const int tid = threadIdx.x;

    if (bid < RB_FEAT) {
        const int b = bid >> 5, tc = bid & 31;
        const int t0 = tc * 64;
        for (int idx = tid; idx < 80 * 64; idx += 256) {
            int cc = idx >> 6, tt = idx & 63;                  // coalesced over tt
            float v = feat[((size_t)b * C_ + cc) * T_ + t0 + tt];
            tile[tt * TILE_S + cc] = (_Float16)v;
        }
        __syncthreads();
        for (int idx = tid; idx < 64 * 10; idx += 256) {
            int tt = idx / 10, g = idx % 10;                   // coalesced writes
            *(f4v*)(featT + ((size_t)b * T_ + t0 + tt) * C_ + g * 8) =
                *(const f4v*)(tile + tt * TILE_S + g * 8);
        }
    } else if (bid < RB_BFRAG) {
        int idx = (bid - RB_FEAT) * 256 + tid;                 // < BF_ELEMS exactly
        int e  = idx & 7;
        int l  = (idx >> 3) & 63;
        int j  = (idx >> 9) & 3;
        int w2 = (idx >> 11) & 1;
        int it = (idx >> 12) % NKI;
        int nt = idx / (NKI << 12);
        int h  = nt * 128 + w2 * 64 + j * 16 + (l & 15);
        int kc = it * 32 + (l >> 4) * 8 + e;
        float v = 0.f;
        if (kc < KTOT) v = enc_w[(h * C_ + kc % 80) * K_ + kc / 80];
        Bf[idx] = (_Float16)v;
    } else {
        const int b = bid - RB_BFRAG;
        int* wob = word_of + b * T_;
        for (int t = tid; t < T_; t += 256) wob[t] = -1;
        __syncthreads();
        if (tid < W_) {
            const int len = lengths[b];
            int s = bounds[(b * 2 + 0) * W_ + tid];
            int e = bounds[(b * 2 + 1) * W_ + tid];
            s = max(s, 0); e = min(e, T_);
            bool valid = (tid < len) && (e > s);
            inv_cnt[b * W_ + tid] = valid ? 1.f / (float)(e - s) : 0.f;
            if (valid)
                for (int t = s; t < e; ++t) wob[t] = tid;      // disjoint words
        }
    }
}

// ---------------------------------------------------------------------------
// Implicit-GEMM conv (f16 MFMA) + bias + ReLU + word mean-pool into wemb.
// R7 = R3 base (TM=128, acc[4][4], LDS A-stage, XCD co-location, hoisted
// epilogue scalars) with:
//  - B global prefetch 3-deep (latency tolerance ~240cyc > L2 ~200cyc);
//    all three preloads issued BEFORE the barrier to ride the stage drain.
//  - Coalesced epilogue: after shfl-reduce, 4 broadcasts + select let all
//    64 lanes store one full 256B row (2 whole lines) instead of 4 x 64B
//    partial-line RMWs.
// ---------------------------------------------------------------------------
__global__ __launch_bounds__(256, 3) void gemm_enc(
    const _Float16* __restrict__ featT,   // (B,T,C)
    const _Float16* __restrict__ Bf,      // wave-order fragments (padded +4 iters)
    const float*    __restrict__ enc_b,   // (H)
    const int*      __restrict__ word_of, // (B,T)
    const float*    __restrict__ inv_cnt, // (B,W)
    float*          __restrict__ wemb)    // (B,W,H)
{
    __shared__ __attribute__((aligned(16))) _Float16 sf[SF_ELEMS];   // 21.25 KB

    const int tid = threadIdx.x;
    // bijective XCD co-location remap: all 4 nt of one g=(b,mt) share bid%8
    const int bid = blockIdx.x;                   // 0..2047
    const int xcd = bid & 7;
    const int u   = bid >> 3;                     // 0..255
    const int nt  = u & 3;
    const int g   = xcd + ((u >> 2) << 3);        // 0..511
    const int b   = g >> 4;
    const int mt  = g & 15;
    const int t0 = mt * TM;
    const int h0 = nt * TN;

    const int lane = tid & 63;
    const int wid  = tid >> 6;
    const int wm = (wid >> 1) * 64;
    const int wn = (wid & 1) * 64;
    const int w2 = wid & 1;
    const int ml = lane & 15;
    const int q  = lane >> 4;

    // ---- stage A tile via global_load_lds (16 B/lane, linear both sides) ----
    {
        const _Float16* fb = featT + (size_t)b * T_ * C_;
        const int fbase = (t0 - 2) * C_;                 // may be <0 (mt==0)
        const int gmax  = T_ * C_ - 8;                   // clamp; garbage re-zeroed
        for (int ch = wid; ch < 22; ch += 4) {           // 21 full + 1 tail chunk
            int loff = (ch << 9) + lane * 8;
            if (loff < SF_ELEMS) {                       // tail: lanes >=16 masked
                int goff = fbase + loff;
                goff = min(max(goff, 0), gmax);
                __builtin_amdgcn_global_load_lds((guint*)(fb + goff),
                                                 (luint*)(sf + (ch << 9)), 16, 0, 0);
            }
        }
    }

    // ---- epilogue scalar prefetch (overlaps staging drain) ----
    const int bT = b * T_;
    const int bW = b * W_;
    int wlo[4], whi[4];
    unsigned ownm = 0;
    {
        int wpv[4], wnx[4];
        #pragma unroll
        for (int i = 0; i < 4; ++i) {
            const int tg = t0 + wm + i * 16;
            wlo[i] = word_of[bT + tg];
            whi[i] = word_of[bT + tg + 15];
            wpv[i] = (tg == 0)       ? -2 : word_of[bT + tg - 1];
            wnx[i] = (tg + 16 >= T_) ? -2 : word_of[bT + tg + 16];
        }
        #pragma unroll
        for (int i = 0; i < 4; ++i)
            if (wpv[i] != wlo[i] && wnx[i] != wlo[i]) ownm |= (1u << i);
    }

    // ---- B fragment stream: preload it0/it1/it2 BEFORE the barrier ----
    const half8* bfp = (const half8*)(Bf + (((nt * NKI) * 2 + w2) * 4 * 64 + lane) * 8);
    half8 b0[4], b1[4], b2[4];
    #pragma unroll
    for (int j = 0; j < 4; ++j) b0[j] = bfp[j * 64];
    #pragma unroll
    for (int j = 0; j < 4; ++j) b1[j] = bfp[512 + j * 64];
    #pragma unroll
    for (int j = 0; j < 4; ++j) b2[j] = bfp[1024 + j * 64];

    __syncthreads();   // drains global_load_lds (vmcnt) + barrier

    // SAME-pad rows outside [0,T) hold clamp-garbage in edge blocks: zero them.
    if (mt == 0) {                       // rows 0,1 (t=-2,-1): 160 f16 = 20 f4v
        if (tid < 20) ((f4v*)sf)[tid] = (f4v){};
        __syncthreads();
    }
    if (mt == 15) {                      // rows 130..135 (t>=2048): 60 f4v
        if (tid < 60) ((f4v*)(sf + 130 * SF_STRIDE))[tid] = (f4v){};
        __syncthreads();
    }

    f4v acc[4][4] = {};

    // A addressing is linear: af(it,i) = sf + abase + it*32 + i*16*80
    const int abase = (wm + ml) * SF_STRIDE + q * 8;

    // preload A(it0)
    half8 acur[4];
    #pragma unroll
    for (int i = 0; i < 4; ++i)
        acur[i] = *(const half8*)(sf + abase + i * 16 * SF_STRIDE);

    #pragma unroll
    for (int it = 0; it < NKI; ++it) {
        half8 anxt[4], bnn[4];
        #pragma unroll
        for (int i = 0; i < 4; ++i)      // A(it+1); max offset < SF_ELEMS (slack)
            anxt[i] = *(const half8*)(sf + abase + (it + 1) * 32 + i * 16 * SF_STRIDE);
        {                                // B(it+3); Bf padded +4 iters (dead loads ok)
            const half8* bn = bfp + (it + 3) * 512;
            #pragma unroll
            for (int j = 0; j < 4; ++j) bnn[j] = bn[j * 64];
        }
        #pragma unroll
        for (int i = 0; i < 4; ++i)
            #pragma unroll
            for (int j = 0; j < 4; ++j)
                acc[i][j] = __builtin_amdgcn_mfma_f32_16x16x32_f16(acur[i], b0[j], acc[i][j], 0, 0, 0);
        #pragma unroll
        for (int i = 0; i < 4; ++i) acur[i] = anxt[i];
        #pragma unroll
        for (int j = 0; j < 4; ++j) { b0[j] = b1[j]; b1[j] = b2[j]; b2[j] = bnn[j]; }
    }

    // ---- epilogue: bias + ReLU + mean-pool; coalesced full-row stores ----
    float bias[4], invp[4];
    #pragma unroll
    for (int j = 0; j < 4; ++j) bias[j] = enc_b[h0 + wn + j * 16 + ml];
    #pragma unroll
    for (int i = 0; i < 4; ++i) invp[i] = inv_cnt[bW + max(wlo[i], 0)];

    #pragma unroll
    for (int i = 0; i < 4; ++i) {
        const int tg = t0 + wm + i * 16;
        const int w0  = wlo[i];
        const int w15 = whi[i];
        if (w0 == w15) {
            if (w0 >= 0) {
                const float inv = invp[i];
                const bool own = (ownm >> i) & 1;
                float sj[4];
                #pragma unroll
                for (int j = 0; j < 4; ++j) {
                    float s = 0.f;
                    #pragma unroll
                    for (int r = 0; r < 4; ++r) s += fmaxf(acc[i][j][r] + bias[j], 0.f);
                    s += __shfl_down(s, 32, 64);
                    s += __shfl_down(s, 16, 64);
                    sj[j] = s;                      // full sum valid on lanes 0..15
                }
                // redistribute: lane L holds row value for column wn + L
                float v0 = __shfl(sj[0], ml, 64);
                float v1 = __shfl(sj[1], ml, 64);
                float v2 = __shfl(sj[2], ml, 64);
                float v3 = __shfl(sj[3], ml, 64);
                float vv = (q == 0) ? v0 : (q == 1) ? v1 : (q == 2) ? v2 : v3;
                float val = vv * inv;
                float* dst = &wemb[(size_t)(bW + w0) * H_ + h0 + wn + lane];
                if (own) *dst = val;                // 64 lanes: 256B coalesced
                else atomicAdd(dst, val);
            }
        } else {
            #pragma unroll
            for (int j = 0; j < 4; ++j) {
                #pragma unroll
                for (int r = 0; r < 4; ++r) {
                    int t = tg + q * 4 + r;
                    int w = word_of[bT + t];
                    if (w >= 0)
                        atomicAdd(&wemb[(size_t)(bW + w) * H_ + h0 + wn + j * 16 + ml],
                                  fmaxf(acc[i][j][r] + bias[j], 0.f) * inv_cnt[bW + w]);
                }
            }
        }
    }
}

// ---------------------------------------------------------------------------
// Decoder: 512 blocks (b x 16 chunks of 8 words) for latency-hiding
// ---------------------------------------------------------------------------
__global__ __launch_bounds__(256) void dec_all(const float* __restrict__ wemb,
                                               const float* __restrict__ dec_w,
                                               const float* __restrict__ dec_b,
                                               float* __restrict__ out) {
    __shared__ float sdw[H_ * K_];       // 10.2 KB
    __shared__ float se[16][8];          // 12 rows used, k-stride 8
    const int bid = blockIdx.x;          // b*16 + ch
    const int b = bid >> 4, ch = bid & 15;
    const int w0 = ch * 8;
    for (int idx = threadIdx.x; idx < H_ * K_; idx += 256) sdw[idx] = dec_w[idx];
    __syncthreads();
    const int wid = threadIdx.x >> 6, lane = threadIdx.x & 63;
    for (int row = wid; row < 12; row += 4) {
        int wq = w0 - 2 + row;
        float a[K_] = {};
        if (wq >= 0 && wq < W_) {
            const float* src = wemb + ((size_t)b * W_ + wq) * H_;
            #pragma unroll
            for (int r = 0; r < H_ / 64; ++r) {
                int h = r * 64 + lane;
                float v = src[h];
                #pragma unroll
                for (int k = 0; k < K_; ++k) a[k] += v * sdw[h * K_ + k];
            }
        }
        #pragma unroll
        for (int k = 0; k < K_; ++k) {
            #pragma unroll
            for (int off = 32; off > 0; off >>= 1) a[k] += __shfl_down(a[k], off, 64);
        }
        if (lane == 0) {
            #pragma unroll
            for (int k = 0; k < K_; ++k) se[row][k] = a[k];
        }
    }
    __syncthreads();
    if (threadIdx.x < 8) {
        int wl = threadIdx.x;
        float acc = dec_b[0];
        #pragma unroll
        for (int k = 0; k < K_; ++k) acc += se[wl + k][k];
        out[b * W_ + w0 + wl] = acc;
    }
}

// ---------------------------------------------------------------------------
extern "C" void kernel_launch(void* const* d_in, const int* in_sizes, int n_in,
                              void* d_out, int out_size, void* d_ws, size_t ws_size,
                              hipStream_t stream) {
    const float* feat    = (const float*)d_in[0];
    const int*   bounds  = (const int*)  d_in[1];
    const int*   lengths = (const int*)  d_in[2];
    const float* enc_w   = (const float*)d_in[3];
    const float* enc_b   = (const float*)d_in[4];
    const float* dec_w   = (const float*)d_in[5];
    const float* dec_b   = (const float*)d_in[6];
    float* out = (float*)d_out;

    char* p = (char*)d_ws;
    _Float16* featT = (_Float16*)p;  p += (size_t)B_ * T_ * C_ * 2;                 // 10.49 MB
    _Float16* Bf    = (_Float16*)p;  p += (size_t)(BF_ELEMS + 4 * ITER_STRIDE) * 2; // 0.44 MB (+4-iter pad)
    int* word_of    = (int*)p;       p += (size_t)B_ * T_ * 4;                      // 0.26 MB
    float* inv_cnt  = (float*)p;     p += (size_t)B_ * W_ * 4;                      // 16 KB
    float* wemb     = (float*)p;                                                    // 8.39 MB (no pre-zero needed)

    prep_all<<<RB_WORDS, 256, 0, stream>>>(feat, enc_w, bounds, lengths,
                                           featT, Bf, word_of, inv_cnt);
    gemm_enc<<<B_ * (T_ / TM) * (H_ / TN), 256, 0, stream>>>(
        featT, Bf, enc_b, word_of, inv_cnt, wemb);
    dec_all<<<B_ * 16, 256, 0, stream>>>(wemb, dec_w, dec_b, out);
}